// Round 3
// baseline (256.408 us; speedup 1.0000x reference)
//
#include <hip/hip_runtime.h>
#include <stdint.h>
#include <stddef.h>

// Problem constants
#define BSZ 128
#define CIN 32
#define COUT 32
#define HN 4096
#define K7 7
#define NTOT (BSZ*CIN*HN)     // 16,777,216 elements
#define NBH  (BSZ*HN)         // 524,288 (b,h) pairs

typedef __attribute__((ext_vector_type(8))) short short8;
typedef __attribute__((ext_vector_type(4))) float f32x4;
// clang-native vector types for nontemporal builtins (HIP uint4/float4 are
// structs -> rejected by __builtin_nontemporal_*)
typedef __attribute__((ext_vector_type(4))) unsigned int u32x4;
typedef __attribute__((ext_vector_type(2))) unsigned int u32x2;

// ws layout (bytes). NOTE: xt lives in the UPPER HALF OF d_out (d_out is 67MB
// f32; xt is 33.5MB bf16, dead before kbn overwrites d_out).
#define WS_OB   0            // bf16 out_pre[B][COUT][H]     : 33,554,432 B
#define WS_WT   33554432     // bf16 wt[o][kk][c]            : 14,336 B
#define WS_NBR  33568768     // int32 nbr_pack[H][8]         : 131,072 B
#define WS_INVD 33699840     // float invd[H]                : 16,384 B
#define WS_OSTP 33716224     // float ostatp[256][64]        : 65,536 B
#define WS_OST  33781760     // float ostat[64] = {sc[32], sh[32]} : 256 B
#define WS_CTR  33782016     // uint32 done-counter           : 4 B

__device__ __forceinline__ unsigned short f32_to_bf16(float f){
    union { float f; uint32_t u; } v; v.f = f;
    uint32_t u = v.u;
    return (unsigned short)((u + 0x7FFFu + ((u >> 16) & 1u)) >> 16);
}
__device__ __forceinline__ float bf16_to_f32(unsigned short h){
    union { uint32_t u; float f; } v; v.u = ((uint32_t)h) << 16;
    return v.f;
}

// ---------------------------------------------------------------------------
// ktrans: pure transpose x[B][C][H] f32 -> xt[B][H][C] bf16 (no stats).
// grid = 128 b * 16 h-tiles(256h) = 2048 blocks of 256.
// Streamed data (x read-once, xt write-once-read-next-kernel) uses
// nontemporal hints so it never pollutes L2 (xt is consumed by a DIFFERENT
// XCD anyway — it must round-trip through L3 regardless).
// kinit's work is folded in: blocks 0..15 build neighbor table + invd + zero
// ostatp; block 16 packs weights + zeroes the kconv done-counter.
__global__ void ktrans(const float* __restrict__ x,
                       unsigned short* __restrict__ xt,
                       const int* __restrict__ nbr,
                       const float* __restrict__ w,
                       int* __restrict__ nbr_pack,
                       float* __restrict__ invd,
                       unsigned short* __restrict__ wt,
                       float* __restrict__ ostatp,
                       unsigned int* __restrict__ ctr){
    __shared__ float tile[32][260];       // rows 16B-aligned (260*4=1040)
    int b  = blockIdx.x >> 4;
    int h0 = (blockIdx.x & 15) << 8;
    int t  = threadIdx.x;
    #pragma unroll
    for (int l = 0; l < 8; l++){
        int linear = l*256 + t;
        int c  = linear >> 6;
        int h4 = linear & 63;
        f32x4 v = __builtin_nontemporal_load(
            (const f32x4*)(x + ((size_t)(b*CIN + c))*HN + h0 + h4*4));
        *(f32x4*)&tile[c][h4*4] = v;      // contiguous b128 stores: conflict-free
    }
    __syncthreads();
    int cg = (t & 3) * 8;
    int hw = t >> 2;                      // 0..63
    #pragma unroll
    for (int r = 0; r < 4; r++){
        int h = r*64 + hw;
        alignas(16) unsigned short tmp[8];
        #pragma unroll
        for (int j = 0; j < 8; j++) tmp[j] = f32_to_bf16(tile[cg + j][h]);
        __builtin_nontemporal_store(*(const u32x4*)tmp,
            (u32x4*)(xt + ((size_t)(b*HN + h0 + h))*32 + cg));
    }
    // ---- folded kinit work (no extra sync needed; independent of above) ----
    if (blockIdx.x < 16){
        int h = blockIdx.x*256 + t;       // 0..4095
        #pragma unroll
        for (int j = 0; j < 4; j++) ostatp[h*4 + j] = 0.0f;   // 16384 floats
        int cnt = 0;
        int pk[8];
        #pragma unroll
        for (int j = 0; j < 6; j++){
            int iv = nbr[h*6 + j];
            if (iv >= HN) iv = HN - 1;    // safety clamp (never expected)
            if (iv >= 0) cnt++; else iv = -1;
            pk[j] = iv;
        }
        pk[6] = cnt; pk[7] = 0;
        #pragma unroll
        for (int j = 0; j < 8; j++) nbr_pack[h*8 + j] = pk[j];
        invd[h] = 1.0f / ((float)cnt + 1.0f + 1e-6f);
    } else if (blockIdx.x == 16){
        if (t == 0) *ctr = 0u;            // re-arm kconv's last-block latch
        for (int i = t; i < COUT*K7*CIN; i += 256){
            int o  = i / (K7*CIN);
            int kk = (i / CIN) % K7;
            int c  = i % CIN;
            wt[i] = f32_to_bf16(w[(o*CIN + c)*K7 + kk]);
        }
    }
}

// ---------------------------------------------------------------------------
// kconv: gather + MFMA + /D, write bf16 out_pre, accumulate BN stat partials.
// XCD-locality swizzle: blk&7 = XCD slot; each XCD works on 16 b's only, so
// its 4MB L2 holds exactly those xt slices (16 x 256KB) -> gathers are L2 hits.
// CRITICAL: ob stores are NONTEMPORAL. The xt working set per XCD (4MB) is
// exactly L2-sized; write-allocating the 4MB/XCD ob stream was evicting xt,
// pushing ~440MB of gather line-traffic to L3 (the measured 40.7us ==
// ~11TB/s of L3 reads, with MfmaUtil at 6.5%). nt keeps xt L2-resident.
// Tail: last block to finish (device-scope counter) folds ostatp->sc/sh,
// eliminating the kred launch + its whole-GPU bubble.
__global__ __launch_bounds__(256) void kconv(
    const unsigned short* __restrict__ xt,
    const unsigned short* __restrict__ wt,
    const int* __restrict__ nbrp,
    const float* __restrict__ invd,
    unsigned short* __restrict__ ob,
    float* __restrict__ ostatp,
    float* __restrict__ ostat,
    const float* __restrict__ gamma,
    const float* __restrict__ beta,
    unsigned int* __restrict__ ctr)
{
    // per-wave output staging: [o][h] with stride 72 shorts (144B = 9*16B:
    // row starts stay 16B-aligned for b128 reads; banks spread o*4 apart).
    __shared__ unsigned short otile[4][32][72];   // 18,432 B
    __shared__ float rpart[4][64];                // last-block reduce scratch
    __shared__ int slast;

    int lane = threadIdx.x & 63;
    int wv   = threadIdx.x >> 6;
    int n    = lane & 15;
    int quad = lane >> 4;
    int xcd  = blockIdx.x & 7;
    int j    = blockIdx.x >> 3;           // 0..255
    int b    = xcd*16 + (j >> 4);
    int hbase= ((j & 15)*4 + wv) * 64;    // this wave: h in [hbase, hbase+64)

    // A fragments (W): lane holds W[o=n+16mt][ik=kk*32 + quad*8 + jj]
    short8 af[2][K7];
    #pragma unroll
    for (int mt = 0; mt < 2; mt++){
        int o = n + 16*mt;
        #pragma unroll
        for (int kk = 0; kk < K7; kk++)
            af[mt][kk] = *(const short8*)(wt + (size_t)(o*K7 + kk)*CIN + quad*8);
    }

    float sacc[8]  = {0,0,0,0,0,0,0,0};
    float sacc2[8] = {0,0,0,0,0,0,0,0};
    const short8 zero8 = {0,0,0,0,0,0,0,0};
    const unsigned short* xb = xt + (size_t)b*HN*CIN;

    // prefetch tile 0's neighbor rows + invd
    int h = hbase + n;
    int4 na = *(const int4*)(nbrp + h*8);
    int4 nb = *(const int4*)(nbrp + h*8 + 4);
    float idv = invd[h];

    #pragma unroll 1
    for (int it = 0; it < 4; it++){
        // prefetch next tile's table entries (dummy-reload current on last)
        int hn = hbase + (it < 3 ? it+1 : it)*16 + n;
        int4 na2 = *(const int4*)(nbrp + hn*8);
        int4 nb2 = *(const int4*)(nbrp + hn*8 + 4);
        float idv2 = invd[hn];

        int hc = hbase + it*16 + n;
        short8 bfr[K7];
        bfr[0] = *(const short8*)(xb + (size_t)hc*CIN + quad*8);   // self tap
        int rows[6] = {na.x, na.y, na.z, na.w, nb.x, nb.y};
        #pragma unroll
        for (int kk = 0; kk < 6; kk++){
            int row  = rows[kk];
            int rowc = row < 0 ? 0 : row;
            bfr[kk+1] = *(const short8*)(xb + (size_t)rowc*CIN + quad*8);
            if (row < 0) bfr[kk+1] = zero8;
        }
        f32x4 acc0 = {0.f,0.f,0.f,0.f};
        f32x4 acc1 = {0.f,0.f,0.f,0.f};
        #pragma unroll
        for (int kk = 0; kk < K7; kk++){
            acc0 = __builtin_amdgcn_mfma_f32_16x16x32_bf16(af[0][kk], bfr[kk], acc0, 0, 0, 0);
            acc1 = __builtin_amdgcn_mfma_f32_16x16x32_bf16(af[1][kk], bfr[kk], acc1, 0, 0, 0);
        }
        // epilogue: D[row=quad*4+r][col=n]; o = mt*16+quad*4+r -> stage in LDS
        #pragma unroll
        for (int mt = 0; mt < 2; mt++){
            f32x4 a = mt ? acc1 : acc0;
            #pragma unroll
            for (int r = 0; r < 4; r++){
                int o = mt*16 + quad*4 + r;
                float v = a[r]*idv;
                otile[wv][o][it*16 + n] = f32_to_bf16(v);
                sacc[mt*4 + r]  += v;
                sacc2[mt*4 + r] += v*v;
            }
        }
        na = na2; nb = nb2; idv = idv2;
    }

    // wave-private tile -> coalesced NONTEMPORAL global stores (no L2 alloc).
    #pragma unroll
    for (int ro = 0; ro < 4; ro++){
        int o  = ro*8 + (lane >> 3);
        int hh = (lane & 7)*8;
        u32x4 vv = *(const u32x4*)&otile[wv][o][hh];
        __builtin_nontemporal_store(vv,
            (u32x4*)(ob + ((size_t)(b*COUT + o))*HN + hbase + hh));
    }

    // reduce BN partials over the 16 n-lanes
    #pragma unroll
    for (int bit = 1; bit < 16; bit <<= 1){
        #pragma unroll
        for (int i = 0; i < 8; i++){
            sacc[i]  += __shfl_xor(sacc[i],  bit);
            sacc2[i] += __shfl_xor(sacc2[i], bit);
        }
    }
    if (n == 0){
        int slot = blockIdx.x & 255;
        #pragma unroll
        for (int mt = 0; mt < 2; mt++)
            #pragma unroll
            for (int r = 0; r < 4; r++){
                int o = mt*16 + quad*4 + r;
                atomicAdd(&ostatp[slot*64 + o],      sacc[mt*4 + r]);
                atomicAdd(&ostatp[slot*64 + 32 + o], sacc2[mt*4 + r]);
            }
    }

    // ---- last-block-done: fold ostatp[256][64] -> sc/sh (replaces kred) ----
    __syncthreads();
    if (threadIdx.x == 0){
        __threadfence();                          // ostatp atomics visible
        unsigned d = atomicAdd(ctr, 1u);
        slast = (d == 2047u);
    }
    __syncthreads();
    if (!slast) return;
    // Only the final block runs this. ostatp lines were only ever touched by
    // device-scope atomics (coherent point) — plain loads cannot be stale.
    {
        int t = threadIdx.x;
        int a = t & 63, g = t >> 6;
        float s = 0.0f;
        #pragma unroll
        for (int jj = 0; jj < 64; jj++)
            s += ostatp[((g << 6) + jj)*64 + a];
        rpart[g][a] = s;
        __syncthreads();
        if (t < 64)
            rpart[0][t] = rpart[0][t] + rpart[1][t] + rpart[2][t] + rpart[3][t];
        __syncthreads();
        if (t < 32){
            float mean = rpart[0][t]      * (1.0f/(float)NBH);
            float var  = rpart[0][32 + t] * (1.0f/(float)NBH) - mean*mean;
            float sc = gamma[t] * rsqrtf(var + 1e-5f);
            ostat[t]      = sc;
            ostat[32 + t] = beta[t] - mean*sc;
        }
    }
}

// ---------------------------------------------------------------------------
// kbn: read bf16 out_pre, apply precomputed scale/shift, write f32 d_out.
// Per-thread: one u32x2 (4 bf16) load -> one f32x4 store, so every store
// instruction is a DENSE 1KB/wave line write (the old i*2/i*2+1 pair wrote
// 16B every 32B per instruction). Both streams nontemporal (read/write once).
__global__ void kbn(const unsigned short* __restrict__ ob,
                    float* __restrict__ out,
                    const float* __restrict__ ostat){
    __shared__ float sc[32], sh[32];
    int t = threadIdx.x;
    if (t < 32){ sc[t] = ostat[t]; sh[t] = ostat[32 + t]; }
    __syncthreads();
    int gid = blockIdx.x*256 + t;
    const u32x2* ob2 = (const u32x2*)ob;
    f32x4* out4 = (f32x4*)out;
    #pragma unroll
    for (int k = 0; k < 8; k++){
        int i = gid + k*(2048*256);               // i < NTOT/4 = 4,194,304
        int o = (i >> 10) & 31;                   // (i*4 / 4096) % 32
        u32x2 raw = __builtin_nontemporal_load(ob2 + i);
        const unsigned short* p = (const unsigned short*)&raw;
        float s = sc[o], bsh = sh[o];
        f32x4 r;
        r.x = bf16_to_f32(p[0])*s + bsh;
        r.y = bf16_to_f32(p[1])*s + bsh;
        r.z = bf16_to_f32(p[2])*s + bsh;
        r.w = bf16_to_f32(p[3])*s + bsh;
        __builtin_nontemporal_store(r, out4 + i);
    }
}

// ---------------------------------------------------------------------------
extern "C" void kernel_launch(void* const* d_in, const int* in_sizes, int n_in,
                              void* d_out, int out_size, void* d_ws, size_t ws_size,
                              hipStream_t stream) {
    const float* x      = (const float*)d_in[0];
    const float* weight = (const float*)d_in[1];
    // d_in[2] = bias  — exactly cancelled by BatchNorm mean subtraction
    const float* gamma  = (const float*)d_in[3];
    const float* beta   = (const float*)d_in[4];
    const int*   nbr    = (const int*)d_in[5];   // int64 in reference -> int32 from harness
    // d_in[6] = groups (==1), ignored

    char* ws = (char*)d_ws;
    unsigned short* ob    = (unsigned short*)(ws + WS_OB);
    unsigned short* wt    = (unsigned short*)(ws + WS_WT);
    int*            nbrp  = (int*)(ws + WS_NBR);
    float*          invd  = (float*)(ws + WS_INVD);
    float*          ostatp= (float*)(ws + WS_OSTP);
    float*          ostat = (float*)(ws + WS_OST);
    unsigned int*   ctr   = (unsigned int*)(ws + WS_CTR);
    float*          out   = (float*)d_out;
    // xt (bf16, 33.5MB) lives in the upper half of d_out; dead before kbn
    // overwrites d_out (stream-ordered).
    unsigned short* xt    = (unsigned short*)d_out + 16777216;

    ktrans<<<2048, 256, 0, stream>>>(x, xt, nbr, weight, nbrp, invd, wt, ostatp, ctr);
    kconv <<<2048, 256, 0, stream>>>(xt, wt, nbrp, invd, ob, ostatp, ostat, gamma, beta, ctr);
    kbn   <<<2048, 256, 0, stream>>>(ob, out, ostat);
}

// Round 4
// 190.903 us; speedup vs baseline: 1.3431x; 1.3431x over previous
//
#include <hip/hip_runtime.h>
#include <stdint.h>
#include <stddef.h>

// Problem constants
#define BSZ 128
#define CIN 32
#define COUT 32
#define HN 4096
#define K7 7
#define NTOT (BSZ*CIN*HN)     // 16,777,216 elements
#define NBH  (BSZ*HN)         // 524,288 (b,h) pairs

typedef __attribute__((ext_vector_type(8))) short short8;
typedef __attribute__((ext_vector_type(4))) float f32x4;
// clang-native vector types for nontemporal builtins (HIP uint4/float4 are
// structs -> rejected by __builtin_nontemporal_*)
typedef __attribute__((ext_vector_type(4))) unsigned int u32x4;
typedef __attribute__((ext_vector_type(2))) unsigned int u32x2;

// ws layout (bytes). NOTE: xt lives in the UPPER HALF OF d_out (d_out is 67MB
// f32; xt is 33.5MB bf16, dead before kbn overwrites d_out).
#define WS_OB   0            // bf16 out_pre[B][COUT][H]     : 33,554,432 B
#define WS_WT   33554432     // bf16 wt[o][kk][c]            : 14,336 B
#define WS_NBR  33568768     // int32 nbr_pack[H][8]         : 131,072 B
#define WS_INVD 33699840     // float invd[H]                : 16,384 B
#define WS_OSTP 33716224     // float ostatp[256][64]        : 65,536 B
#define WS_OST  33781760     // float ostat[64] = {sc[32], sh[32]} : 256 B

__device__ __forceinline__ unsigned short f32_to_bf16(float f){
    union { float f; uint32_t u; } v; v.f = f;
    uint32_t u = v.u;
    return (unsigned short)((u + 0x7FFFu + ((u >> 16) & 1u)) >> 16);
}
__device__ __forceinline__ float bf16_to_f32(unsigned short h){
    union { uint32_t u; float f; } v; v.u = ((uint32_t)h) << 16;
    return v.f;
}

// ---------------------------------------------------------------------------
// ktrans: pure transpose x[B][C][H] f32 -> xt[B][H][C] bf16 (no stats).
// grid = 128 b * 16 h-tiles(256h) = 2048 blocks of 256.
// Streamed data (x read-once, xt write-once-read-next-kernel) uses
// nontemporal hints so it never pollutes L2 (xt is consumed by a DIFFERENT
// XCD anyway — it must round-trip through L3 regardless).
// kinit's work is folded in: blocks 0..15 build neighbor table + invd + zero
// ostatp; block 16 packs weights.
__global__ void ktrans(const float* __restrict__ x,
                       unsigned short* __restrict__ xt,
                       const int* __restrict__ nbr,
                       const float* __restrict__ w,
                       int* __restrict__ nbr_pack,
                       float* __restrict__ invd,
                       unsigned short* __restrict__ wt,
                       float* __restrict__ ostatp){
    __shared__ float tile[32][260];       // rows 16B-aligned (260*4=1040)
    int b  = blockIdx.x >> 4;
    int h0 = (blockIdx.x & 15) << 8;
    int t  = threadIdx.x;
    #pragma unroll
    for (int l = 0; l < 8; l++){
        int linear = l*256 + t;
        int c  = linear >> 6;
        int h4 = linear & 63;
        f32x4 v = __builtin_nontemporal_load(
            (const f32x4*)(x + ((size_t)(b*CIN + c))*HN + h0 + h4*4));
        *(f32x4*)&tile[c][h4*4] = v;      // contiguous b128 stores: conflict-free
    }
    __syncthreads();
    int cg = (t & 3) * 8;
    int hw = t >> 2;                      // 0..63
    #pragma unroll
    for (int r = 0; r < 4; r++){
        int h = r*64 + hw;
        alignas(16) unsigned short tmp[8];
        #pragma unroll
        for (int j = 0; j < 8; j++) tmp[j] = f32_to_bf16(tile[cg + j][h]);
        __builtin_nontemporal_store(*(const u32x4*)tmp,
            (u32x4*)(xt + ((size_t)(b*HN + h0 + h))*32 + cg));
    }
    // ---- folded kinit work (no extra sync needed; independent of above) ----
    if (blockIdx.x < 16){
        int h = blockIdx.x*256 + t;       // 0..4095
        #pragma unroll
        for (int j = 0; j < 4; j++) ostatp[h*4 + j] = 0.0f;   // 16384 floats
        int cnt = 0;
        int pk[8];
        #pragma unroll
        for (int j = 0; j < 6; j++){
            int iv = nbr[h*6 + j];
            if (iv >= HN) iv = HN - 1;    // safety clamp (never expected)
            if (iv >= 0) cnt++; else iv = -1;
            pk[j] = iv;
        }
        pk[6] = cnt; pk[7] = 0;
        #pragma unroll
        for (int j = 0; j < 8; j++) nbr_pack[h*8 + j] = pk[j];
        invd[h] = 1.0f / ((float)cnt + 1.0f + 1e-6f);
    } else if (blockIdx.x == 16){
        for (int i = t; i < COUT*K7*CIN; i += 256){
            int o  = i / (K7*CIN);
            int kk = (i / CIN) % K7;
            int c  = i % CIN;
            wt[i] = f32_to_bf16(w[(o*CIN + c)*K7 + kk]);
        }
    }
}

// ---------------------------------------------------------------------------
// kconv: gather + MFMA + /D, write bf16 out_pre, accumulate BN stat partials.
// XCD-locality swizzle: blk&7 = XCD slot; each XCD works on 16 b's only, so
// its 4MB L2 holds exactly those xt slices (16 x 256KB) -> gathers are L2 hits.
// ob stores are NONTEMPORAL: the xt working set per XCD (4MB) is exactly
// L2-sized; write-allocating the 4MB/XCD ob stream would evict xt.
// R3 LESSON: do NOT put __threadfence() in this kernel's tail — the
// agent-scope release fence emits an L2-writeback op per block (2048 of them)
// which tripled kconv's duration at identical FETCH/WRITE volumes.
__global__ __launch_bounds__(256) void kconv(
    const unsigned short* __restrict__ xt,
    const unsigned short* __restrict__ wt,
    const int* __restrict__ nbrp,
    const float* __restrict__ invd,
    unsigned short* __restrict__ ob,
    float* __restrict__ ostatp)
{
    // per-wave output staging: [o][h] with stride 72 shorts (144B = 9*16B:
    // row starts stay 16B-aligned for b128 reads; banks spread o*4 apart).
    __shared__ unsigned short otile[4][32][72];   // 18,432 B

    int lane = threadIdx.x & 63;
    int wv   = threadIdx.x >> 6;
    int n    = lane & 15;
    int quad = lane >> 4;
    int xcd  = blockIdx.x & 7;
    int j    = blockIdx.x >> 3;           // 0..255
    int b    = xcd*16 + (j >> 4);
    int hbase= ((j & 15)*4 + wv) * 64;    // this wave: h in [hbase, hbase+64)

    // A fragments (W): lane holds W[o=n+16mt][ik=kk*32 + quad*8 + jj]
    short8 af[2][K7];
    #pragma unroll
    for (int mt = 0; mt < 2; mt++){
        int o = n + 16*mt;
        #pragma unroll
        for (int kk = 0; kk < K7; kk++)
            af[mt][kk] = *(const short8*)(wt + (size_t)(o*K7 + kk)*CIN + quad*8);
    }

    float sacc[8]  = {0,0,0,0,0,0,0,0};
    float sacc2[8] = {0,0,0,0,0,0,0,0};
    const short8 zero8 = {0,0,0,0,0,0,0,0};
    const unsigned short* xb = xt + (size_t)b*HN*CIN;

    // prefetch tile 0's neighbor rows + invd
    int h = hbase + n;
    int4 na = *(const int4*)(nbrp + h*8);
    int4 nb = *(const int4*)(nbrp + h*8 + 4);
    float idv = invd[h];

    #pragma unroll 1
    for (int it = 0; it < 4; it++){
        // prefetch next tile's table entries (dummy-reload current on last)
        int hn = hbase + (it < 3 ? it+1 : it)*16 + n;
        int4 na2 = *(const int4*)(nbrp + hn*8);
        int4 nb2 = *(const int4*)(nbrp + hn*8 + 4);
        float idv2 = invd[hn];

        int hc = hbase + it*16 + n;
        short8 bfr[K7];
        bfr[0] = *(const short8*)(xb + (size_t)hc*CIN + quad*8);   // self tap
        int rows[6] = {na.x, na.y, na.z, na.w, nb.x, nb.y};
        #pragma unroll
        for (int kk = 0; kk < 6; kk++){
            int row  = rows[kk];
            int rowc = row < 0 ? 0 : row;
            bfr[kk+1] = *(const short8*)(xb + (size_t)rowc*CIN + quad*8);
            if (row < 0) bfr[kk+1] = zero8;
        }
        f32x4 acc0 = {0.f,0.f,0.f,0.f};
        f32x4 acc1 = {0.f,0.f,0.f,0.f};
        #pragma unroll
        for (int kk = 0; kk < K7; kk++){
            acc0 = __builtin_amdgcn_mfma_f32_16x16x32_bf16(af[0][kk], bfr[kk], acc0, 0, 0, 0);
            acc1 = __builtin_amdgcn_mfma_f32_16x16x32_bf16(af[1][kk], bfr[kk], acc1, 0, 0, 0);
        }
        // epilogue: D[row=quad*4+r][col=n]; o = mt*16+quad*4+r -> stage in LDS
        #pragma unroll
        for (int mt = 0; mt < 2; mt++){
            f32x4 a = mt ? acc1 : acc0;
            #pragma unroll
            for (int r = 0; r < 4; r++){
                int o = mt*16 + quad*4 + r;
                float v = a[r]*idv;
                otile[wv][o][it*16 + n] = f32_to_bf16(v);
                sacc[mt*4 + r]  += v;
                sacc2[mt*4 + r] += v*v;
            }
        }
        na = na2; nb = nb2; idv = idv2;
    }

    // wave-private tile -> coalesced NONTEMPORAL global stores (no L2 alloc).
    #pragma unroll
    for (int ro = 0; ro < 4; ro++){
        int o  = ro*8 + (lane >> 3);
        int hh = (lane & 7)*8;
        u32x4 vv = *(const u32x4*)&otile[wv][o][hh];
        __builtin_nontemporal_store(vv,
            (u32x4*)(ob + ((size_t)(b*COUT + o))*HN + hbase + hh));
    }

    // reduce BN partials over the 16 n-lanes
    #pragma unroll
    for (int bit = 1; bit < 16; bit <<= 1){
        #pragma unroll
        for (int i = 0; i < 8; i++){
            sacc[i]  += __shfl_xor(sacc[i],  bit);
            sacc2[i] += __shfl_xor(sacc2[i], bit);
        }
    }
    if (n == 0){
        int slot = blockIdx.x & 255;
        #pragma unroll
        for (int mt = 0; mt < 2; mt++)
            #pragma unroll
            for (int r = 0; r < 4; r++){
                int o = mt*16 + quad*4 + r;
                atomicAdd(&ostatp[slot*64 + o],      sacc[mt*4 + r]);
                atomicAdd(&ostatp[slot*64 + 32 + o], sacc2[mt*4 + r]);
            }
    }
}

// ---------------------------------------------------------------------------
// kred: fold ostatp[256][64] -> ostat = {sc[32], sh[32]}. One block of 256.
__global__ void kred(const float* __restrict__ ostatp,
                     float* __restrict__ ostat,
                     const float* __restrict__ gamma,
                     const float* __restrict__ beta){
    __shared__ float part[4][64];
    int t = threadIdx.x;
    int a = t & 63;
    int g = t >> 6;
    float s = 0.0f;
    #pragma unroll
    for (int j = 0; j < 64; j++)
        s += ostatp[(g*64 + j)*64 + a];
    part[g][a] = s;
    __syncthreads();
    if (t < 64)
        part[0][t] = part[0][t] + part[1][t] + part[2][t] + part[3][t];
    __syncthreads();
    if (t < 32){
        float mean = part[0][t]      * (1.0f/(float)NBH);
        float var  = part[0][32 + t] * (1.0f/(float)NBH) - mean*mean;
        float sc = gamma[t] * rsqrtf(var + 1e-5f);
        ostat[t]      = sc;
        ostat[32 + t] = beta[t] - mean*sc;
    }
}

// ---------------------------------------------------------------------------
// kbn: read bf16 out_pre, apply precomputed scale/shift, write f32 d_out.
// Per-thread: one u32x2 (4 bf16) load -> one f32x4 store, so every store
// instruction is a DENSE 1KB/wave line write. Both streams nontemporal
// (read-once / write-once).
__global__ void kbn(const unsigned short* __restrict__ ob,
                    float* __restrict__ out,
                    const float* __restrict__ ostat){
    __shared__ float sc[32], sh[32];
    int t = threadIdx.x;
    if (t < 32){ sc[t] = ostat[t]; sh[t] = ostat[32 + t]; }
    __syncthreads();
    int gid = blockIdx.x*256 + t;
    const u32x2* ob2 = (const u32x2*)ob;
    f32x4* out4 = (f32x4*)out;
    #pragma unroll
    for (int k = 0; k < 8; k++){
        int i = gid + k*(2048*256);               // i < NTOT/4 = 4,194,304
        int o = (i >> 10) & 31;                   // (i*4 / 4096) % 32
        u32x2 raw = __builtin_nontemporal_load(ob2 + i);
        const unsigned short* p = (const unsigned short*)&raw;
        float s = sc[o], bsh = sh[o];
        f32x4 r;
        r.x = bf16_to_f32(p[0])*s + bsh;
        r.y = bf16_to_f32(p[1])*s + bsh;
        r.z = bf16_to_f32(p[2])*s + bsh;
        r.w = bf16_to_f32(p[3])*s + bsh;
        __builtin_nontemporal_store(r, out4 + i);
    }
}

// ---------------------------------------------------------------------------
extern "C" void kernel_launch(void* const* d_in, const int* in_sizes, int n_in,
                              void* d_out, int out_size, void* d_ws, size_t ws_size,
                              hipStream_t stream) {
    const float* x      = (const float*)d_in[0];
    const float* weight = (const float*)d_in[1];
    // d_in[2] = bias  — exactly cancelled by BatchNorm mean subtraction
    const float* gamma  = (const float*)d_in[3];
    const float* beta   = (const float*)d_in[4];
    const int*   nbr    = (const int*)d_in[5];   // int64 in reference -> int32 from harness
    // d_in[6] = groups (==1), ignored

    char* ws = (char*)d_ws;
    unsigned short* ob    = (unsigned short*)(ws + WS_OB);
    unsigned short* wt    = (unsigned short*)(ws + WS_WT);
    int*            nbrp  = (int*)(ws + WS_NBR);
    float*          invd  = (float*)(ws + WS_INVD);
    float*          ostatp= (float*)(ws + WS_OSTP);
    float*          ostat = (float*)(ws + WS_OST);
    float*          out   = (float*)d_out;
    // xt (bf16, 33.5MB) lives in the upper half of d_out; dead before kbn
    // overwrites d_out (stream-ordered).
    unsigned short* xt    = (unsigned short*)d_out + 16777216;

    ktrans<<<2048, 256, 0, stream>>>(x, xt, nbr, weight, nbrp, invd, wt, ostatp);
    kconv <<<2048, 256, 0, stream>>>(xt, wt, nbrp, invd, ob, ostatp);
    kred  <<<1,    256, 0, stream>>>(ostatp, ostat, gamma, beta);
    kbn   <<<2048, 256, 0, stream>>>(ob, out, ostat);
}

// Round 6
// 184.821 us; speedup vs baseline: 1.3873x; 1.0329x over previous
//
#include <hip/hip_runtime.h>
#include <stdint.h>
#include <stddef.h>

// Problem constants
#define BSZ 128
#define CIN 32
#define COUT 32
#define HN 4096
#define K7 7
#define NTOT (BSZ*CIN*HN)     // 16,777,216 elements
#define NBH  (BSZ*HN)         // 524,288 (b,h) pairs

typedef __attribute__((ext_vector_type(8))) short short8;
typedef __attribute__((ext_vector_type(4))) float f32x4;
typedef __attribute__((ext_vector_type(4))) unsigned int u32x4;
typedef __attribute__((ext_vector_type(2))) unsigned int u32x2;

// ws layout (bytes). NOTE: xt lives in the UPPER HALF OF d_out (d_out is 67MB
// f32; xt is 33.5MB bf16, dead before kbn overwrites d_out).
#define WS_OB   0            // bf16 out_pre[B][COUT][H]     : 33,554,432 B
#define WS_WT   33554432     // bf16 wt[o][kk][c]            : 14,336 B
#define WS_NBR  33568768     // int32 nbr_pack[H][8]         : 131,072 B
#define WS_INVD 33699840     // float invd[H]                : 16,384 B
#define WS_OSTP 33716224     // float ostatp[256][64]        : 65,536 B
#define WS_OST  33781760     // float ostat[64] = {sc[32], sh[32]} : 256 B

// R3 LESSON: no __threadfence() in wide kernels (per-block L2-writeback op
// tripled kconv at identical traffic).
// R4 LESSON: __builtin_nontemporal_* is NET NEGATIVE here on every stream
// (kconv +13%, ktrans/kbn +10us total) — gfx950 nt evidently skips L3
// allocation too. All accesses are plain.

__device__ __forceinline__ unsigned short f32_to_bf16(float f){
    union { float f; uint32_t u; } v; v.f = f;
    uint32_t u = v.u;
    return (unsigned short)((u + 0x7FFFu + ((u >> 16) & 1u)) >> 16);
}
__device__ __forceinline__ float bf16_to_f32(unsigned short h){
    union { uint32_t u; float f; } v; v.u = ((uint32_t)h) << 16;
    return v.f;
}

// ---------------------------------------------------------------------------
// ktrans: transpose x[B][C][H] f32 -> PAIRED xt[bp][h][p][c] bf16, where
// b = 2*bp + p. One 128B line now holds the SAME h-row for both b's of a
// pair — kconv's random-row gathers use every fetched byte (was 50%).
// grid = 64 bp * 16 h-tiles(256h) = 1024 blocks of 256; each block loops
// over its two b's. kinit fold: blocks 0..15 neighbor table + invd + zero
// ostatp; block 16 packs weights.
__global__ void ktrans(const float* __restrict__ x,
                       unsigned short* __restrict__ xt,
                       const int* __restrict__ nbr,
                       const float* __restrict__ w,
                       int* __restrict__ nbr_pack,
                       float* __restrict__ invd,
                       unsigned short* __restrict__ wt,
                       float* __restrict__ ostatp){
    __shared__ float tile[32][260];       // rows 16B-aligned (260*4=1040)
    int bp = blockIdx.x >> 4;             // 0..63
    int h0 = (blockIdx.x & 15) << 8;
    int t  = threadIdx.x;
    #pragma unroll 1
    for (int bb = 0; bb < 2; bb++){
        int b = bp*2 + bb;
        if (bb) __syncthreads();          // protect tile reuse across halves
        #pragma unroll
        for (int l = 0; l < 8; l++){
            int linear = l*256 + t;
            int c  = linear >> 6;
            int h4 = linear & 63;
            f32x4 v = *(const f32x4*)(x + ((size_t)(b*CIN + c))*HN + h0 + h4*4);
            *(f32x4*)&tile[c][h4*4] = v;  // contiguous b128 stores: conflict-free
        }
        __syncthreads();
        int cg = (t & 3) * 8;
        int hw = t >> 2;                  // 0..63
        #pragma unroll
        for (int r = 0; r < 4; r++){
            int h = r*64 + hw;
            alignas(16) unsigned short tmp[8];
            #pragma unroll
            for (int j = 0; j < 8; j++) tmp[j] = f32_to_bf16(tile[cg + j][h]);
            // paired layout: shorts index = bp*HN*64 + h*64 + bb*32 + c
            *(u32x4*)(xt + (size_t)bp*HN*64 + (size_t)(h0 + h)*64 + bb*32 + cg)
                = *(const u32x4*)tmp;
        }
    }
    // ---- folded kinit work ----
    if (blockIdx.x < 16){
        int h = blockIdx.x*256 + t;       // 0..4095
        #pragma unroll
        for (int j = 0; j < 4; j++) ostatp[h*4 + j] = 0.0f;   // 16384 floats
        int cnt = 0;
        int pk[8];
        #pragma unroll
        for (int j = 0; j < 6; j++){
            int iv = nbr[h*6 + j];
            if (iv >= HN) iv = HN - 1;    // safety clamp (never expected)
            if (iv >= 0) cnt++; else iv = -1;
            pk[j] = iv;
        }
        pk[6] = cnt; pk[7] = 0;
        #pragma unroll
        for (int j = 0; j < 8; j++) nbr_pack[h*8 + j] = pk[j];
        invd[h] = 1.0f / ((float)cnt + 1.0f + 1e-6f);
    } else if (blockIdx.x == 16){
        for (int i = t; i < COUT*K7*CIN; i += 256){
            int o  = i / (K7*CIN);
            int kk = (i / CIN) % K7;
            int c  = i % CIN;
            wt[i] = f32_to_bf16(w[(o*CIN + c)*K7 + kk]);
        }
    }
}

// ---------------------------------------------------------------------------
// kconv: gather + MFMA + /D for a b-PAIR per block. Each gathered 128B line
// feeds MFMAs for BOTH b's (4 independent acc chains, 28 MFMAs/iter) —
// halves gather line traffic (~436MB -> ~235MB) and doubles per-iter load
// ILP. 1024 blocks of 256: blk&7 = XCD slot (8 bp = 16 b per XCD -> 4MB L2
// working set); block = (bp, 256 h); wave = 64 h = 4 tiles x 16 h.
// Output staged per-wave in LDS, written as full 128B lines.
__global__ __launch_bounds__(256, 4) void kconv(
    const unsigned short* __restrict__ xt,
    const unsigned short* __restrict__ wt,
    const int* __restrict__ nbrp,
    const float* __restrict__ invd,
    unsigned short* __restrict__ ob,
    float* __restrict__ ostatp)
{
    // per-wave staging: [p][o][h] stride 72 shorts (144B = 9*16B: rows stay
    // 16B-aligned for b128 reads; o*36%32 spreads banks).
    __shared__ unsigned short otile[4][2][32][72];   // 36,864 B -> 4 blk/CU

    int lane = threadIdx.x & 63;
    int wv   = threadIdx.x >> 6;
    int n    = lane & 15;
    int quad = lane >> 4;
    int xcd  = blockIdx.x & 7;
    int j    = blockIdx.x >> 3;           // 0..127
    int bp   = xcd*8 + (j >> 4);          // 0..63
    int hbase= ((j & 15)*4 + wv) * 64;    // this wave: h in [hbase, hbase+64)

    // A fragments (W): lane holds W[o=n+16mt][ik=kk*32 + quad*8 + jj]
    short8 af[2][K7];
    #pragma unroll
    for (int mt = 0; mt < 2; mt++){
        int o = n + 16*mt;
        #pragma unroll
        for (int kk = 0; kk < K7; kk++)
            af[mt][kk] = *(const short8*)(wt + (size_t)(o*K7 + kk)*CIN + quad*8);
    }

    float sacc[8]  = {0,0,0,0,0,0,0,0};
    float sacc2[8] = {0,0,0,0,0,0,0,0};
    const short8 zero8 = {0,0,0,0,0,0,0,0};
    const unsigned short* xb = xt + (size_t)bp*HN*64;   // 64 shorts per (bp,h)

    // prefetch tile 0's neighbor rows + invd
    int h = hbase + n;
    int4 na = *(const int4*)(nbrp + h*8);
    int4 nb = *(const int4*)(nbrp + h*8 + 4);
    float idv = invd[h];

    #pragma unroll 1
    for (int it = 0; it < 4; it++){
        // prefetch next tile's table entries (dummy-reload current on last)
        int hn = hbase + (it < 3 ? it+1 : it)*16 + n;
        int4 na2 = *(const int4*)(nbrp + hn*8);
        int4 nb2 = *(const int4*)(nbrp + hn*8 + 4);
        float idv2 = invd[hn];

        int hc = hbase + it*16 + n;
        short8 bfr[K7][2];
        {
            const unsigned short* rp = xb + (size_t)hc*64 + quad*8;
            bfr[0][0] = *(const short8*)(rp);        // self tap, b even
            bfr[0][1] = *(const short8*)(rp + 32);   // self tap, b odd
        }
        int rows[6] = {na.x, na.y, na.z, na.w, nb.x, nb.y};
        #pragma unroll
        for (int kk = 0; kk < 6; kk++){
            int row  = rows[kk];
            int rowc = row < 0 ? 0 : row;
            const unsigned short* rp = xb + (size_t)rowc*64 + quad*8;
            short8 v0 = *(const short8*)(rp);
            short8 v1 = *(const short8*)(rp + 32);
            if (row < 0){ v0 = zero8; v1 = zero8; }
            bfr[kk+1][0] = v0;
            bfr[kk+1][1] = v1;
        }
        f32x4 acc00 = {0.f,0.f,0.f,0.f};   // p=0, o-tile 0
        f32x4 acc01 = {0.f,0.f,0.f,0.f};   // p=0, o-tile 1
        f32x4 acc10 = {0.f,0.f,0.f,0.f};   // p=1, o-tile 0
        f32x4 acc11 = {0.f,0.f,0.f,0.f};   // p=1, o-tile 1
        #pragma unroll
        for (int kk = 0; kk < K7; kk++){
            acc00 = __builtin_amdgcn_mfma_f32_16x16x32_bf16(af[0][kk], bfr[kk][0], acc00, 0, 0, 0);
            acc01 = __builtin_amdgcn_mfma_f32_16x16x32_bf16(af[1][kk], bfr[kk][0], acc01, 0, 0, 0);
            acc10 = __builtin_amdgcn_mfma_f32_16x16x32_bf16(af[0][kk], bfr[kk][1], acc10, 0, 0, 0);
            acc11 = __builtin_amdgcn_mfma_f32_16x16x32_bf16(af[1][kk], bfr[kk][1], acc11, 0, 0, 0);
        }
        // epilogue: D[row=quad*4+r][col=n]; o = mt*16+quad*4+r
        #pragma unroll
        for (int p = 0; p < 2; p++){
            #pragma unroll
            for (int mt = 0; mt < 2; mt++){
                f32x4 a = p ? (mt ? acc11 : acc10) : (mt ? acc01 : acc00);
                #pragma unroll
                for (int r = 0; r < 4; r++){
                    int o = mt*16 + quad*4 + r;
                    float v = a[r]*idv;
                    otile[wv][p][o][it*16 + n] = f32_to_bf16(v);
                    sacc[mt*4 + r]  += v;
                    sacc2[mt*4 + r] += v*v;
                }
            }
        }
        na = na2; nb = nb2; idv = idv2;
    }

    // wave-private tiles -> coalesced global stores (full 128B lines/instr).
    #pragma unroll
    for (int p = 0; p < 2; p++){
        #pragma unroll
        for (int ro = 0; ro < 4; ro++){
            int o  = ro*8 + (lane >> 3);
            int hh = (lane & 7)*8;
            u32x4 vv = *(const u32x4*)&otile[wv][p][o][hh];
            *(u32x4*)(ob + ((size_t)((bp*2 + p)*COUT + o))*HN + hbase + hh) = vv;
        }
    }

    // reduce BN partials over the 16 n-lanes
    #pragma unroll
    for (int bit = 1; bit < 16; bit <<= 1){
        #pragma unroll
        for (int i = 0; i < 8; i++){
            sacc[i]  += __shfl_xor(sacc[i],  bit);
            sacc2[i] += __shfl_xor(sacc2[i], bit);
        }
    }
    if (n == 0){
        int slot = blockIdx.x & 255;
        #pragma unroll
        for (int mt = 0; mt < 2; mt++)
            #pragma unroll
            for (int r = 0; r < 4; r++){
                int o = mt*16 + quad*4 + r;
                atomicAdd(&ostatp[slot*64 + o],      sacc[mt*4 + r]);
                atomicAdd(&ostatp[slot*64 + 32 + o], sacc2[mt*4 + r]);
            }
    }
}

// ---------------------------------------------------------------------------
// kred: fold ostatp[256][64] -> ostat = {sc[32], sh[32]}. One block of 256.
__global__ void kred(const float* __restrict__ ostatp,
                     float* __restrict__ ostat,
                     const float* __restrict__ gamma,
                     const float* __restrict__ beta){
    __shared__ float part[4][64];
    int t = threadIdx.x;
    int a = t & 63;
    int g = t >> 6;
    float s = 0.0f;
    #pragma unroll
    for (int j = 0; j < 64; j++)
        s += ostatp[(g*64 + j)*64 + a];
    part[g][a] = s;
    __syncthreads();
    if (t < 64)
        part[0][t] = part[0][t] + part[1][t] + part[2][t] + part[3][t];
    __syncthreads();
    if (t < 32){
        float mean = part[0][t]      * (1.0f/(float)NBH);
        float var  = part[0][32 + t] * (1.0f/(float)NBH) - mean*mean;
        float sc = gamma[t] * rsqrtf(var + 1e-5f);
        ostat[t]      = sc;
        ostat[32 + t] = beta[t] - mean*sc;
    }
}

// ---------------------------------------------------------------------------
// kbn: read bf16 out_pre, apply precomputed scale/shift, write f32 d_out.
// Per-thread: one u32x2 (4 bf16) load -> one f32x4 store => every store
// instruction is a DENSE 1KB/wave line write. Plain accesses (R4: nt hurt).
__global__ void kbn(const unsigned short* __restrict__ ob,
                    float* __restrict__ out,
                    const float* __restrict__ ostat){
    __shared__ float sc[32], sh[32];
    int t = threadIdx.x;
    if (t < 32){ sc[t] = ostat[t]; sh[t] = ostat[32 + t]; }
    __syncthreads();
    int gid = blockIdx.x*256 + t;
    const u32x2* ob2 = (const u32x2*)ob;
    f32x4* out4 = (f32x4*)out;
    #pragma unroll
    for (int k = 0; k < 8; k++){
        int i = gid + k*(2048*256);               // i < NTOT/4 = 4,194,304
        int o = (i >> 10) & 31;                   // (i*4 / 4096) % 32
        u32x2 raw = *(ob2 + i);
        const unsigned short* p = (const unsigned short*)&raw;
        float s = sc[o], bsh = sh[o];
        f32x4 r;
        r.x = bf16_to_f32(p[0])*s + bsh;
        r.y = bf16_to_f32(p[1])*s + bsh;
        r.z = bf16_to_f32(p[2])*s + bsh;
        r.w = bf16_to_f32(p[3])*s + bsh;
        *(out4 + i) = r;
    }
}

// ---------------------------------------------------------------------------
extern "C" void kernel_launch(void* const* d_in, const int* in_sizes, int n_in,
                              void* d_out, int out_size, void* d_ws, size_t ws_size,
                              hipStream_t stream) {
    const float* x      = (const float*)d_in[0];
    const float* weight = (const float*)d_in[1];
    // d_in[2] = bias  — exactly cancelled by BatchNorm mean subtraction
    const float* gamma  = (const float*)d_in[3];
    const float* beta   = (const float*)d_in[4];
    const int*   nbr    = (const int*)d_in[5];   // int64 in reference -> int32 from harness
    // d_in[6] = groups (==1), ignored

    char* ws = (char*)d_ws;
    unsigned short* ob    = (unsigned short*)(ws + WS_OB);
    unsigned short* wt    = (unsigned short*)(ws + WS_WT);
    int*            nbrp  = (int*)(ws + WS_NBR);
    float*          invd  = (float*)(ws + WS_INVD);
    float*          ostatp= (float*)(ws + WS_OSTP);
    float*          ostat = (float*)(ws + WS_OST);
    float*          out   = (float*)d_out;
    // xt (bf16 paired, 33.5MB) lives in the upper half of d_out; dead before
    // kbn overwrites d_out (stream-ordered).
    unsigned short* xt    = (unsigned short*)d_out + 16777216;

    ktrans<<<1024, 256, 0, stream>>>(x, xt, nbr, weight, nbrp, invd, wt, ostatp);
    kconv <<<1024, 256, 0, stream>>>(xt, wt, nbrp, invd, ob, ostatp);
    kred  <<<1,    256, 0, stream>>>(ostatp, ostat, gamma, beta);
    kbn   <<<2048, 256, 0, stream>>>(ob, out, ostat);
}

// Round 7
// 180.229 us; speedup vs baseline: 1.4227x; 1.0255x over previous
//
#include <hip/hip_runtime.h>
#include <stdint.h>
#include <stddef.h>

// Problem constants
#define BSZ 128
#define CIN 32
#define COUT 32
#define HN 4096
#define K7 7
#define NTOT (BSZ*CIN*HN)     // 16,777,216 elements
#define NBH  (BSZ*HN)         // 524,288 (b,h) pairs

typedef __attribute__((ext_vector_type(8))) short short8;
typedef __attribute__((ext_vector_type(4))) float f32x4;
typedef __attribute__((ext_vector_type(4))) unsigned int u32x4;
typedef __attribute__((ext_vector_type(2))) unsigned int u32x2;

// ws layout (bytes). NOTE: xt lives in the UPPER HALF OF d_out (d_out is 67MB
// f32; xt is 33.5MB bf16, dead before kbn overwrites d_out).
#define WS_OB   0            // bf16 out_pre[B][COUT][H]     : 33,554,432 B
#define WS_WT   33554432     // bf16 wt[o][kk][c]            : 14,336 B
#define WS_NBR  33568768     // int32 nbr_pack[H][8]         : 131,072 B
#define WS_INVD 33699840     // float invd[H]                : 16,384 B
#define WS_OSTP 33716224     // float ostatp[256][64]        : 65,536 B
#define WS_OST  33781760     // float ostat[64] = {sc[32], sh[32]} : 256 B

// LESSONS LEDGER:
// R3: no __threadfence() in wide kernels (per-block L2-writeback op tripled
//     kconv at identical traffic).
// R4: __builtin_nontemporal_* is NET NEGATIVE on every stream here (gfx950
//     nt skips L3 allocation too). All accesses plain.
// R6: halving gather *line* traffic (b-pair packing) changed nothing; kconv
//     is NOT line-BW bound. Model: time ≈ line-requests x avg-miss-latency /
//     MSHR-depth. Lever = avg latency (make gathers L2-hits).

__device__ __forceinline__ unsigned short f32_to_bf16(float f){
    union { float f; uint32_t u; } v; v.f = f;
    uint32_t u = v.u;
    return (unsigned short)((u + 0x7FFFu + ((u >> 16) & 1u)) >> 16);
}
__device__ __forceinline__ float bf16_to_f32(unsigned short h){
    union { uint32_t u; float f; } v; v.u = ((uint32_t)h) << 16;
    return v.f;
}

// ---------------------------------------------------------------------------
// ktrans: transpose x[B][C][H] f32 -> xt[B][H][C] bf16 (flat, R1 layout).
// grid = 128 b * 16 h-tiles(256h) = 2048 blocks of 256.
// kinit fold: blocks 0..15 neighbor table + invd + zero ostatp; block 16
// packs weights.
__global__ void ktrans(const float* __restrict__ x,
                       unsigned short* __restrict__ xt,
                       const int* __restrict__ nbr,
                       const float* __restrict__ w,
                       int* __restrict__ nbr_pack,
                       float* __restrict__ invd,
                       unsigned short* __restrict__ wt,
                       float* __restrict__ ostatp){
    __shared__ float tile[32][260];       // rows 16B-aligned (260*4=1040)
    int b  = blockIdx.x >> 4;
    int h0 = (blockIdx.x & 15) << 8;
    int t  = threadIdx.x;
    #pragma unroll
    for (int l = 0; l < 8; l++){
        int linear = l*256 + t;
        int c  = linear >> 6;
        int h4 = linear & 63;
        f32x4 v = *(const f32x4*)(x + ((size_t)(b*CIN + c))*HN + h0 + h4*4);
        *(f32x4*)&tile[c][h4*4] = v;      // contiguous b128 stores: conflict-free
    }
    __syncthreads();
    int cg = (t & 3) * 8;
    int hw = t >> 2;                      // 0..63
    #pragma unroll
    for (int r = 0; r < 4; r++){
        int h = r*64 + hw;
        alignas(16) unsigned short tmp[8];
        #pragma unroll
        for (int j = 0; j < 8; j++) tmp[j] = f32_to_bf16(tile[cg + j][h]);
        *(u32x4*)(xt + ((size_t)(b*HN + h0 + h))*32 + cg) = *(const u32x4*)tmp;
    }
    // ---- folded kinit work (independent of above; no extra sync needed) ----
    if (blockIdx.x < 16){
        int h = blockIdx.x*256 + t;       // 0..4095
        #pragma unroll
        for (int j = 0; j < 4; j++) ostatp[h*4 + j] = 0.0f;   // 16384 floats
        int cnt = 0;
        int pk[8];
        #pragma unroll
        for (int j = 0; j < 6; j++){
            int iv = nbr[h*6 + j];
            if (iv >= HN) iv = HN - 1;    // safety clamp (never expected)
            if (iv >= 0) cnt++; else iv = -1;
            pk[j] = iv;
        }
        pk[6] = cnt; pk[7] = 0;
        #pragma unroll
        for (int j = 0; j < 8; j++) nbr_pack[h*8 + j] = pk[j];
        invd[h] = 1.0f / ((float)cnt + 1.0f + 1e-6f);
    } else if (blockIdx.x == 16){
        for (int i = t; i < COUT*K7*CIN; i += 256){
            int o  = i / (K7*CIN);
            int kk = (i / CIN) % K7;
            int c  = i % CIN;
            wt[i] = f32_to_bf16(w[(o*CIN + c)*K7 + kk]);
        }
    }
}

// ---------------------------------------------------------------------------
// kconv: gather + MFMA + /D, write bf16 out_pre, accumulate BN stat partials.
// R1 structure: 2048 blocks of 256; blk&7 = XCD slot (16 b per XCD -> 4MB L2
// working set); block = (b, 256 h); wave = 64 h = 4 tiles x 16 h.
// NEW (R7): L2-WARM PROLOGUE. Each block linearly streams its OWN 16KB h-tile
// of its b's xt slice (the b's 16 co-resident blocks cover the whole 256KB),
// pulling xt into the XCD's L2 with linear high-BW reads BEFORE the random
// gathers need it. Rationale: kconv is pinned at 40-46us across all layout/
// store variants; the only fitting model is scattered-miss latency through a
// fixed MSHR window (~14.3K line-req/CU x ~450-900cyc / ~64). FETCH=18MB
// shows ~8% of gather lines come from HBM (L3 doesn't retain ktrans's
// writes); warming converts the gather's latency mix to ~L2-hit latency.
__global__ __launch_bounds__(256) void kconv(
    const unsigned short* __restrict__ xt,
    const unsigned short* __restrict__ wt,
    const int* __restrict__ nbrp,
    const float* __restrict__ invd,
    unsigned short* __restrict__ ob,
    float* __restrict__ ostatp)
{
    // per-wave output staging: [o][h] with stride 72 shorts (144B = 9*16B:
    // row starts stay 16B-aligned for b128 reads; banks spread o*4 apart).
    __shared__ unsigned short otile[4][32][72];   // 18,432 B -> 8 blk/CU

    int lane = threadIdx.x & 63;
    int wv   = threadIdx.x >> 6;
    int n    = lane & 15;
    int quad = lane >> 4;
    int xcd  = blockIdx.x & 7;
    int j    = blockIdx.x >> 3;           // 0..255
    int b    = xcd*16 + (j >> 4);
    int hbase= ((j & 15)*4 + wv) * 64;    // this wave: h in [hbase, hbase+64)

    const unsigned short* xb = xt + (size_t)b*HN*CIN;

    // ---- L2-warm prologue: stream this block's 256-row (16KB) slice ----
    // One row (64B) per thread, as 4x16B linear loads; results kept live by
    // an empty asm so the loads must execute. Issued FIRST so they're the
    // oldest in the vmcnt queue.
    {
        const u32x4* wp = (const u32x4*)(xb + (size_t)((j & 15)*256 + threadIdx.x)*CIN);
        u32x4 w0 = wp[0];
        u32x4 w1 = wp[1];
        u32x4 w2 = wp[2];
        u32x4 w3 = wp[3];
        asm volatile("" :: "v"(w0), "v"(w1), "v"(w2), "v"(w3));
    }

    // A fragments (W): lane holds W[o=n+16mt][ik=kk*32 + quad*8 + jj]
    short8 af[2][K7];
    #pragma unroll
    for (int mt = 0; mt < 2; mt++){
        int o = n + 16*mt;
        #pragma unroll
        for (int kk = 0; kk < K7; kk++)
            af[mt][kk] = *(const short8*)(wt + (size_t)(o*K7 + kk)*CIN + quad*8);
    }

    float sacc[8]  = {0,0,0,0,0,0,0,0};
    float sacc2[8] = {0,0,0,0,0,0,0,0};
    const short8 zero8 = {0,0,0,0,0,0,0,0};

    // prefetch tile 0's neighbor rows + invd
    int h = hbase + n;
    int4 na = *(const int4*)(nbrp + h*8);
    int4 nb = *(const int4*)(nbrp + h*8 + 4);
    float idv = invd[h];

    #pragma unroll 1
    for (int it = 0; it < 4; it++){
        // prefetch next tile's table entries (dummy-reload current on last)
        int hn = hbase + (it < 3 ? it+1 : it)*16 + n;
        int4 na2 = *(const int4*)(nbrp + hn*8);
        int4 nb2 = *(const int4*)(nbrp + hn*8 + 4);
        float idv2 = invd[hn];

        int hc = hbase + it*16 + n;
        short8 bfr[K7];
        bfr[0] = *(const short8*)(xb + (size_t)hc*CIN + quad*8);   // self tap
        int rows[6] = {na.x, na.y, na.z, na.w, nb.x, nb.y};
        #pragma unroll
        for (int kk = 0; kk < 6; kk++){
            int row  = rows[kk];
            int rowc = row < 0 ? 0 : row;
            bfr[kk+1] = *(const short8*)(xb + (size_t)rowc*CIN + quad*8);
            if (row < 0) bfr[kk+1] = zero8;
        }
        f32x4 acc0 = {0.f,0.f,0.f,0.f};
        f32x4 acc1 = {0.f,0.f,0.f,0.f};
        #pragma unroll
        for (int kk = 0; kk < K7; kk++){
            acc0 = __builtin_amdgcn_mfma_f32_16x16x32_bf16(af[0][kk], bfr[kk], acc0, 0, 0, 0);
            acc1 = __builtin_amdgcn_mfma_f32_16x16x32_bf16(af[1][kk], bfr[kk], acc1, 0, 0, 0);
        }
        // epilogue: D[row=quad*4+r][col=n]; o = mt*16+quad*4+r -> stage in LDS
        #pragma unroll
        for (int mt = 0; mt < 2; mt++){
            f32x4 a = mt ? acc1 : acc0;
            #pragma unroll
            for (int r = 0; r < 4; r++){
                int o = mt*16 + quad*4 + r;
                float v = a[r]*idv;
                otile[wv][o][it*16 + n] = f32_to_bf16(v);
                sacc[mt*4 + r]  += v;
                sacc2[mt*4 + r] += v*v;
            }
        }
        na = na2; nb = nb2; idv = idv2;
    }

    // wave-private tile -> coalesced global stores (full 128B line per 8-lane
    // group per instruction, each line written exactly once).
    #pragma unroll
    for (int ro = 0; ro < 4; ro++){
        int o  = ro*8 + (lane >> 3);
        int hh = (lane & 7)*8;
        u32x4 vv = *(const u32x4*)&otile[wv][o][hh];
        *(u32x4*)(ob + ((size_t)(b*COUT + o))*HN + hbase + hh) = vv;
    }

    // reduce BN partials over the 16 n-lanes
    #pragma unroll
    for (int bit = 1; bit < 16; bit <<= 1){
        #pragma unroll
        for (int i = 0; i < 8; i++){
            sacc[i]  += __shfl_xor(sacc[i],  bit);
            sacc2[i] += __shfl_xor(sacc2[i], bit);
        }
    }
    if (n == 0){
        int slot = blockIdx.x & 255;
        #pragma unroll
        for (int mt = 0; mt < 2; mt++)
            #pragma unroll
            for (int r = 0; r < 4; r++){
                int o = mt*16 + quad*4 + r;
                atomicAdd(&ostatp[slot*64 + o],      sacc[mt*4 + r]);
                atomicAdd(&ostatp[slot*64 + 32 + o], sacc2[mt*4 + r]);
            }
    }
}

// ---------------------------------------------------------------------------
// kred: fold ostatp[256][64] -> ostat = {sc[32], sh[32]}. One block of 256.
__global__ void kred(const float* __restrict__ ostatp,
                     float* __restrict__ ostat,
                     const float* __restrict__ gamma,
                     const float* __restrict__ beta){
    __shared__ float part[4][64];
    int t = threadIdx.x;
    int a = t & 63;
    int g = t >> 6;
    float s = 0.0f;
    #pragma unroll
    for (int j = 0; j < 64; j++)
        s += ostatp[(g*64 + j)*64 + a];
    part[g][a] = s;
    __syncthreads();
    if (t < 64)
        part[0][t] = part[0][t] + part[1][t] + part[2][t] + part[3][t];
    __syncthreads();
    if (t < 32){
        float mean = part[0][t]      * (1.0f/(float)NBH);
        float var  = part[0][32 + t] * (1.0f/(float)NBH) - mean*mean;
        float sc = gamma[t] * rsqrtf(var + 1e-5f);
        ostat[t]      = sc;
        ostat[32 + t] = beta[t] - mean*sc;
    }
}

// ---------------------------------------------------------------------------
// kbn: read bf16 out_pre, apply precomputed scale/shift, write f32 d_out.
// Per-thread: one u32x2 (4 bf16) load -> one f32x4 store => every store
// instruction is a DENSE 1KB/wave line write. Plain accesses (R4: nt hurt).
__global__ void kbn(const unsigned short* __restrict__ ob,
                    float* __restrict__ out,
                    const float* __restrict__ ostat){
    __shared__ float sc[32], sh[32];
    int t = threadIdx.x;
    if (t < 32){ sc[t] = ostat[t]; sh[t] = ostat[32 + t]; }
    __syncthreads();
    int gid = blockIdx.x*256 + t;
    const u32x2* ob2 = (const u32x2*)ob;
    f32x4* out4 = (f32x4*)out;
    #pragma unroll
    for (int k = 0; k < 8; k++){
        int i = gid + k*(2048*256);               // i < NTOT/4 = 4,194,304
        int o = (i >> 10) & 31;                   // (i*4 / 4096) % 32
        u32x2 raw = *(ob2 + i);
        const unsigned short* p = (const unsigned short*)&raw;
        float s = sc[o], bsh = sh[o];
        f32x4 r;
        r.x = bf16_to_f32(p[0])*s + bsh;
        r.y = bf16_to_f32(p[1])*s + bsh;
        r.z = bf16_to_f32(p[2])*s + bsh;
        r.w = bf16_to_f32(p[3])*s + bsh;
        *(out4 + i) = r;
    }
}

// ---------------------------------------------------------------------------
extern "C" void kernel_launch(void* const* d_in, const int* in_sizes, int n_in,
                              void* d_out, int out_size, void* d_ws, size_t ws_size,
                              hipStream_t stream) {
    const float* x      = (const float*)d_in[0];
    const float* weight = (const float*)d_in[1];
    // d_in[2] = bias  — exactly cancelled by BatchNorm mean subtraction
    const float* gamma  = (const float*)d_in[3];
    const float* beta   = (const float*)d_in[4];
    const int*   nbr    = (const int*)d_in[5];   // int64 in reference -> int32 from harness
    // d_in[6] = groups (==1), ignored

    char* ws = (char*)d_ws;
    unsigned short* ob    = (unsigned short*)(ws + WS_OB);
    unsigned short* wt    = (unsigned short*)(ws + WS_WT);
    int*            nbrp  = (int*)(ws + WS_NBR);
    float*          invd  = (float*)(ws + WS_INVD);
    float*          ostatp= (float*)(ws + WS_OSTP);
    float*          ostat = (float*)(ws + WS_OST);
    float*          out   = (float*)d_out;
    // xt (bf16, 33.5MB) lives in the upper half of d_out; dead before kbn
    // overwrites d_out (stream-ordered).
    unsigned short* xt    = (unsigned short*)d_out + 16777216;

    ktrans<<<2048, 256, 0, stream>>>(x, xt, nbr, weight, nbrp, invd, wt, ostatp);
    kconv <<<2048, 256, 0, stream>>>(xt, wt, nbrp, invd, ob, ostatp);
    kred  <<<1,    256, 0, stream>>>(ostatp, ostat, gamma, beta);
    kbn   <<<2048, 256, 0, stream>>>(ob, out, ostat);
}